// Round 1
// baseline (2357.338 us; speedup 1.0000x reference)
//
#include <hip/hip_runtime.h>
#include <hip/hip_bf16.h>

#define N_NODES 100000
#define N_EDGES 1600000
#define IN_DIM  500
#define HID     128
#define KDIM    512   // HID * (DEG+1)

// ---------------------------------------------------------------------------
// CSR build: histogram -> scan -> scatter (edge_index constant across layers,
// so build once per launch, reuse for all 3 SpMMs)
// ---------------------------------------------------------------------------

__global__ __launch_bounds__(256) void hist_kernel(const int* __restrict__ ei,
                                                   int* __restrict__ counts) {
    int e = blockIdx.x * 256 + threadIdx.x;
    if (e < N_EDGES) atomicAdd(&counts[ei[e]], 1);
}

__global__ __launch_bounds__(1024) void scan_kernel(const int* __restrict__ counts,
                                                    int* __restrict__ row_start,
                                                    int* __restrict__ cursor) {
    __shared__ int sums[1024];
    const int tid = threadIdx.x;
    const int CH = (N_NODES + 1023) / 1024;  // 98
    int begin = tid * CH;
    int end   = begin + CH; if (end > N_NODES) end = N_NODES;
    int s = 0;
    for (int i = begin; i < end && i < N_NODES; i++) s += counts[i];
    sums[tid] = s;
    __syncthreads();
    // Hillis-Steele inclusive scan
    for (int off = 1; off < 1024; off <<= 1) {
        int v = (tid >= off) ? sums[tid - off] : 0;
        __syncthreads();
        sums[tid] += v;
        __syncthreads();
    }
    int run = (tid == 0) ? 0 : sums[tid - 1];
    for (int i = begin; i < end && i < N_NODES; i++) {
        row_start[i] = run;
        cursor[i]    = run;
        run += counts[i];
    }
    if (tid == 1023) row_start[N_NODES] = sums[1023];
}

__global__ __launch_bounds__(256) void scatter_kernel(const int* __restrict__ ei,
                                                      int* __restrict__ cursor,
                                                      int* __restrict__ col_sorted) {
    int e = blockIdx.x * 256 + threadIdx.x;
    if (e < N_EDGES) {
        int r = ei[e];
        int c = ei[N_EDGES + e];
        int pos = atomicAdd(&cursor[r], 1);
        col_sorted[pos] = c;
    }
}

// ---------------------------------------------------------------------------
// Repack cheb coeffs [l][i][o][d] -> Cmat[l][k=i*4+d][o]  (GEMM-B layout)
// ---------------------------------------------------------------------------
__global__ __launch_bounds__(256) void repack_kernel(const float* __restrict__ cheb,
                                                     float* __restrict__ Cmat) {
    int idx = blockIdx.x * 256 + threadIdx.x;   // < 2*512*128
    int l   = idx >> 16;
    int rem = idx & 65535;
    int k   = rem >> 7;
    int o   = rem & 127;
    int i   = k >> 2;
    int d   = k & 3;
    Cmat[idx] = cheb[l * 65536 + i * 512 + o * 4 + d];
}

// ---------------------------------------------------------------------------
// GEMM1: h = x @ W_in     [100000 x 500] @ [500 x 128]
// 128x128 tile, KT=25, 256 threads, 8x8 microtile
// ---------------------------------------------------------------------------
__global__ __launch_bounds__(256) void gemm_xw(const float* __restrict__ x,
                                               const float* __restrict__ W,
                                               float* __restrict__ out) {
    constexpr int KT = 25;
    __shared__ float As[KT][HID];   // [kk][node]
    __shared__ float Bs[KT][HID];   // [kk][m]
    const int tid = threadIdx.x;
    const int tx = tid & 15;
    const int ty = tid >> 4;
    const int n0 = blockIdx.x * 128;

    float acc[8][8];
#pragma unroll
    for (int i = 0; i < 8; i++)
#pragma unroll
        for (int j = 0; j < 8; j++) acc[i][j] = 0.f;

    for (int k0 = 0; k0 < IN_DIM; k0 += KT) {
        for (int idx = tid; idx < 128 * KT; idx += 256) {
            int node = idx / KT;
            int kk   = idx % KT;
            int n = n0 + node;
            As[kk][node] = (n < N_NODES) ? x[(long)n * IN_DIM + k0 + kk] : 0.f;
        }
        for (int idx = tid; idx < KT * HID; idx += 256) {
            int kk = idx >> 7;
            int m  = idx & 127;
            Bs[kk][m] = W[(k0 + kk) * HID + m];
        }
        __syncthreads();
#pragma unroll
        for (int kk = 0; kk < KT; kk++) {
            float a[8], b[8];
#pragma unroll
            for (int i = 0; i < 8; i++) a[i] = As[kk][ty * 8 + i];
#pragma unroll
            for (int j = 0; j < 8; j++) b[j] = Bs[kk][tx * 8 + j];
#pragma unroll
            for (int i = 0; i < 8; i++)
#pragma unroll
                for (int j = 0; j < 8; j++) acc[i][j] += a[i] * b[j];
        }
        __syncthreads();
    }
#pragma unroll
    for (int i = 0; i < 8; i++) {
        int n = n0 + ty * 8 + i;
        if (n < N_NODES) {
#pragma unroll
            for (int j = 0; j < 8; j++) out[n * HID + tx * 8 + j] = acc[i][j];
        }
    }
}

// ---------------------------------------------------------------------------
// ChebyKAN as GEMM: out = Basis(h) @ Cmat,  [N x 512]@[512 x 128]
// Basis computed on the fly in the A-tile loader (no materialization).
// ---------------------------------------------------------------------------
__global__ __launch_bounds__(256) void cheb_gemm(const float* __restrict__ h,
                                                 const float* __restrict__ Cmat,
                                                 float* __restrict__ out) {
    constexpr int KT = 16;   // 4 h-features per K-tile
    __shared__ float As[KT][HID];
    __shared__ float Bs[KT][HID];
    const int tid = threadIdx.x;
    const int tx = tid & 15;
    const int ty = tid >> 4;
    const int n0 = blockIdx.x * 128;

    float acc[8][8];
#pragma unroll
    for (int i = 0; i < 8; i++)
#pragma unroll
        for (int j = 0; j < 8; j++) acc[i][j] = 0.f;

    for (int k0 = 0; k0 < KDIM; k0 += KT) {
        int i0 = k0 >> 2;   // h feature base (4 features per tile)
        for (int idx = tid; idx < 128 * 4; idx += 256) {
            int node = idx >> 2;
            int ii   = idx & 3;
            int n = n0 + node;
            float hv = (n < N_NODES) ? h[n * HID + i0 + ii] : 0.f;
            float t  = tanhf(hv);
            float T2 = 2.f * t * t - 1.f;
            float T3 = 2.f * t * T2 - t;
            As[ii * 4 + 0][node] = 1.f;
            As[ii * 4 + 1][node] = t;
            As[ii * 4 + 2][node] = T2;
            As[ii * 4 + 3][node] = T3;
        }
        for (int idx = tid; idx < KT * HID; idx += 256) {
            int kk = idx >> 7;
            int m  = idx & 127;
            Bs[kk][m] = Cmat[(k0 + kk) * HID + m];
        }
        __syncthreads();
#pragma unroll
        for (int kk = 0; kk < KT; kk++) {
            float a[8], b[8];
#pragma unroll
            for (int i = 0; i < 8; i++) a[i] = As[kk][ty * 8 + i];
#pragma unroll
            for (int j = 0; j < 8; j++) b[j] = Bs[kk][tx * 8 + j];
#pragma unroll
            for (int i = 0; i < 8; i++)
#pragma unroll
                for (int j = 0; j < 8; j++) acc[i][j] += a[i] * b[j];
        }
        __syncthreads();
    }
#pragma unroll
    for (int i = 0; i < 8; i++) {
        int n = n0 + ty * 8 + i;
        if (n < N_NODES) {
#pragma unroll
            for (int j = 0; j < 8; j++) out[n * HID + tx * 8 + j] = acc[i][j];
        }
    }
}

// ---------------------------------------------------------------------------
// SpMM gather: out[row][:] = sum over CSR range of h[col][:]
// one wave per row, float2 per lane (64 lanes * 8B = 512B row)
// ---------------------------------------------------------------------------
__global__ __launch_bounds__(256) void spmm_gather(const int* __restrict__ row_start,
                                                   const int* __restrict__ col_sorted,
                                                   const float* __restrict__ h,
                                                   float* __restrict__ out) {
    const int wid  = (blockIdx.x * 256 + threadIdx.x) >> 6;   // wave id = row
    const int lane = threadIdx.x & 63;
    if (wid >= N_NODES) return;
    const int s = row_start[wid];
    const int e = row_start[wid + 1];
    const float2* __restrict__ h2 = (const float2*)h;
    float2 acc0 = {0.f, 0.f}, acc1 = {0.f, 0.f};
    int j = s;
    for (; j + 1 < e; j += 2) {
        int c0 = col_sorted[j];
        int c1 = col_sorted[j + 1];
        float2 v0 = h2[c0 * 64 + lane];
        float2 v1 = h2[c1 * 64 + lane];
        acc0.x += v0.x; acc0.y += v0.y;
        acc1.x += v1.x; acc1.y += v1.y;
    }
    if (j < e) {
        int c = col_sorted[j];
        float2 v = h2[c * 64 + lane];
        acc0.x += v.x; acc0.y += v.y;
    }
    acc0.x += acc1.x; acc0.y += acc1.y;
    ((float2*)out)[wid * 64 + lane] = acc0;
}

// ---------------------------------------------------------------------------
// Output GEMM (128->16) + log_softmax, fused. 16 nodes/block, 16 thr/node.
// ---------------------------------------------------------------------------
__global__ __launch_bounds__(256) void out_kernel(const float* __restrict__ h,
                                                  const float* __restrict__ Wo,
                                                  float* __restrict__ out) {
    __shared__ float Ws[HID * 16];
    __shared__ float Hs[16][HID];
    const int tid = threadIdx.x;
    const int n0 = blockIdx.x * 16;
    for (int idx = tid; idx < HID * 16; idx += 256) Ws[idx] = Wo[idx];
    for (int idx = tid; idx < 16 * HID; idx += 256) {
        int nl = idx >> 7;
        int k  = idx & 127;
        Hs[nl][k] = h[(n0 + nl) * HID + k];
    }
    __syncthreads();
    const int nl = tid >> 4;
    const int o  = tid & 15;
    float acc = 0.f;
#pragma unroll
    for (int k = 0; k < HID; k++) acc += Hs[nl][k] * Ws[k * 16 + o];
    // log_softmax across the 16-lane group (masks 1,2,4,8 stay in aligned 16-groups)
    float mx = acc;
#pragma unroll
    for (int m = 8; m >= 1; m >>= 1) mx = fmaxf(mx, __shfl_xor(mx, m));
    float ex = expf(acc - mx);
    float se = ex;
#pragma unroll
    for (int m = 8; m >= 1; m >>= 1) se += __shfl_xor(se, m);
    out[(n0 + nl) * 16 + o] = acc - mx - logf(se);
}

// ---------------------------------------------------------------------------

extern "C" void kernel_launch(void* const* d_in, const int* in_sizes, int n_in,
                              void* d_out, int out_size, void* d_ws, size_t ws_size,
                              hipStream_t stream) {
    const float* x     = (const float*)d_in[0];
    const int*   ei    = (const int*)d_in[1];
    const float* W_in  = (const float*)d_in[2];
    const float* cheb  = (const float*)d_in[3];
    const float* W_out = (const float*)d_in[4];
    float* out = (float*)d_out;

    char* p = (char*)d_ws;
    float* hA        = (float*)p; p += (size_t)N_NODES * HID * 4;     // 51.2 MB
    float* hB        = (float*)p; p += (size_t)N_NODES * HID * 4;     // 51.2 MB
    int*   col_sorted= (int*)p;   p += (size_t)N_EDGES * 4;           // 6.4 MB
    float* Cmat      = (float*)p; p += (size_t)2 * KDIM * HID * 4;    // 0.5 MB
    int*   counts    = (int*)p;   p += (size_t)N_NODES * 4;
    int*   row_start = (int*)p;   p += (size_t)(N_NODES + 1) * 4;
    int*   cursor    = (int*)p;   p += (size_t)N_NODES * 4;

    const int nblk_gemm = (N_NODES + 127) / 128;       // 782
    const int nblk_edge = N_EDGES / 256;               // 6250
    const int nblk_spmm = (N_NODES + 3) / 4;           // 25000 (4 waves/block)
    const int nblk_out  = N_NODES / 16;                // 6250

    hipMemsetAsync(counts, 0, (size_t)N_NODES * 4, stream);
    hist_kernel<<<nblk_edge, 256, 0, stream>>>(ei, counts);
    scan_kernel<<<1, 1024, 0, stream>>>(counts, row_start, cursor);
    scatter_kernel<<<nblk_edge, 256, 0, stream>>>(ei, cursor, col_sorted);
    repack_kernel<<<2 * KDIM * HID / 256, 256, 0, stream>>>(cheb, Cmat);

    gemm_xw<<<nblk_gemm, 256, 0, stream>>>(x, W_in, hA);
    spmm_gather<<<nblk_spmm, 256, 0, stream>>>(row_start, col_sorted, hA, hB);

    cheb_gemm<<<nblk_gemm, 256, 0, stream>>>(hB, Cmat, hA);               // layer 0
    spmm_gather<<<nblk_spmm, 256, 0, stream>>>(row_start, col_sorted, hA, hB);

    cheb_gemm<<<nblk_gemm, 256, 0, stream>>>(hB, Cmat + KDIM * HID, hA);  // layer 1
    spmm_gather<<<nblk_spmm, 256, 0, stream>>>(row_start, col_sorted, hA, hB);

    out_kernel<<<nblk_out, 256, 0, stream>>>(hB, W_out, out);
}

// Round 2
// 1439.802 us; speedup vs baseline: 1.6373x; 1.6373x over previous
//
#include <hip/hip_runtime.h>
#include <hip/hip_bf16.h>

#define N_NODES 100000
#define N_EDGES 1600000
#define IN_DIM  500
#define HID     128
#define KDIM    512   // HID * (DEG+1)

typedef __attribute__((ext_vector_type(8))) short bf16x8;
typedef __attribute__((ext_vector_type(4))) float f32x4;

__device__ inline short f2bf(float x) {
    union { float f; unsigned u; } v; v.f = x;
    unsigned r = (v.u + 0x7FFFu + ((v.u >> 16) & 1u)) >> 16;  // RNE
    return (short)r;
}

// ---------------------------------------------------------------------------
// CSR build: histogram -> scan -> scatter (edge_index constant across layers)
// ---------------------------------------------------------------------------

__global__ __launch_bounds__(256) void hist_kernel(const int* __restrict__ ei,
                                                   int* __restrict__ counts) {
    int e = blockIdx.x * 256 + threadIdx.x;
    if (e < N_EDGES) atomicAdd(&counts[ei[e]], 1);
}

__global__ __launch_bounds__(1024) void scan_kernel(const int* __restrict__ counts,
                                                    int* __restrict__ row_start,
                                                    int* __restrict__ cursor) {
    __shared__ int sums[1024];
    const int tid = threadIdx.x;
    const int CH = (N_NODES + 1023) / 1024;  // 98
    int begin = tid * CH;
    int end   = begin + CH; if (end > N_NODES) end = N_NODES;
    int s = 0;
    for (int i = begin; i < end && i < N_NODES; i++) s += counts[i];
    sums[tid] = s;
    __syncthreads();
    for (int off = 1; off < 1024; off <<= 1) {
        int v = (tid >= off) ? sums[tid - off] : 0;
        __syncthreads();
        sums[tid] += v;
        __syncthreads();
    }
    int run = (tid == 0) ? 0 : sums[tid - 1];
    for (int i = begin; i < end && i < N_NODES; i++) {
        row_start[i] = run;
        cursor[i]    = run;
        run += counts[i];
    }
    if (tid == 1023) row_start[N_NODES] = sums[1023];
}

__global__ __launch_bounds__(256) void scatter_kernel(const int* __restrict__ ei,
                                                      int* __restrict__ cursor,
                                                      int* __restrict__ col_sorted) {
    int e = blockIdx.x * 256 + threadIdx.x;
    if (e < N_EDGES) {
        int r = ei[e];
        int c = ei[N_EDGES + e];
        int pos = atomicAdd(&cursor[r], 1);
        col_sorted[pos] = c;
    }
}

// ---------------------------------------------------------------------------
// Repack cheb coeffs [l][i][o][d] -> Cmat[l][k=i*4+d][o]  (GEMM-B layout)
// ---------------------------------------------------------------------------
__global__ __launch_bounds__(256) void repack_kernel(const float* __restrict__ cheb,
                                                     float* __restrict__ Cmat) {
    int idx = blockIdx.x * 256 + threadIdx.x;   // < 2*512*128
    int l   = idx >> 16;
    int rem = idx & 65535;
    int k   = rem >> 7;
    int o   = rem & 127;
    int i   = k >> 2;
    int d   = k & 3;
    Cmat[idx] = cheb[l * 65536 + i * 512 + o * 4 + d];
}

// ---------------------------------------------------------------------------
// MFMA GEMM 1: h = x @ W_in   [100000 x 500(pad 512)] @ [500 x 128], bf16 MFMA
// 128x128 tile, BK=32, 4 waves/block; wave w computes rows [w*32, w*32+32).
// A rows padded to 40 shorts (80 B) -> ~2-way LDS aliasing (free per m136).
// ---------------------------------------------------------------------------
__global__ __launch_bounds__(256, 3) void gemm_xw(const float* __restrict__ x,
                                                  const float* __restrict__ W,
                                                  float* __restrict__ out) {
    __shared__ __align__(16) short As[128][40];   // [m][k] bf16, row 80 B
    __shared__ __align__(16) short Bs[128][40];   // [n][k] bf16 (B transposed)
    const int tid  = threadIdx.x;
    const int lane = tid & 63;
    const int wave = tid >> 6;
    const int quad = lane >> 4;
    const int l16  = lane & 15;
    const int n0   = blockIdx.x * 128;
    const int lr   = tid >> 1;     // A-stage row 0..127
    const int lh   = tid & 1;      // A-stage half (16 f32 each)

    f32x4 acc[2][8];
#pragma unroll
    for (int mt = 0; mt < 2; mt++)
#pragma unroll
        for (int nt = 0; nt < 8; nt++)
#pragma unroll
            for (int r = 0; r < 4; r++) acc[mt][nt][r] = 0.f;

    for (int kt = 0; kt < 16; kt++) {
        const int k0 = kt * 32;
        // ---- A stage: x[n0+lr][k0+lh*16 .. +15] -> bf16
        {
            int n = n0 + lr; if (n >= N_NODES) n = N_NODES - 1;
            const float* src = x + (long)n * IN_DIM + k0 + lh * 16;
            const int kb = k0 + lh * 16;
            float v[16];
            if (kb + 16 <= IN_DIM) {
                const float4* s4 = (const float4*)src;
                float4 a0 = s4[0], a1 = s4[1], a2 = s4[2], a3 = s4[3];
                v[0]=a0.x; v[1]=a0.y; v[2]=a0.z; v[3]=a0.w;
                v[4]=a1.x; v[5]=a1.y; v[6]=a1.z; v[7]=a1.w;
                v[8]=a2.x; v[9]=a2.y; v[10]=a2.z; v[11]=a2.w;
                v[12]=a3.x; v[13]=a3.y; v[14]=a3.z; v[15]=a3.w;
            } else {
#pragma unroll
                for (int q = 0; q < 16; q++) v[q] = (kb + q < IN_DIM) ? src[q] : 0.f;
            }
            short tmp[16];
#pragma unroll
            for (int q = 0; q < 16; q++) tmp[q] = f2bf(v[q]);
            *(bf16x8*)&As[lr][lh * 16]     = *(bf16x8*)&tmp[0];
            *(bf16x8*)&As[lr][lh * 16 + 8] = *(bf16x8*)&tmp[8];
        }
        // ---- B stage: W[k0+kk][n] -> Bs[n][kk]
        for (int idx = tid; idx < 32 * 128; idx += 256) {
            int kk = idx >> 7;
            int m  = idx & 127;
            float wv = (k0 + kk < IN_DIM) ? W[(k0 + kk) * HID + m] : 0.f;
            Bs[m][kk] = f2bf(wv);
        }
        __syncthreads();
        // ---- MFMA
        bf16x8 a0 = *(const bf16x8*)&As[wave * 32 + l16][quad * 8];
        bf16x8 a1 = *(const bf16x8*)&As[wave * 32 + 16 + l16][quad * 8];
#pragma unroll
        for (int nt = 0; nt < 8; nt++) {
            bf16x8 b = *(const bf16x8*)&Bs[nt * 16 + l16][quad * 8];
            acc[0][nt] = __builtin_amdgcn_mfma_f32_16x16x32_bf16(a0, b, acc[0][nt], 0, 0, 0);
            acc[1][nt] = __builtin_amdgcn_mfma_f32_16x16x32_bf16(a1, b, acc[1][nt], 0, 0, 0);
        }
        __syncthreads();
    }
    // ---- store: C[row=quad*4+r][col=l16] per 16x16 tile
#pragma unroll
    for (int mt = 0; mt < 2; mt++) {
        int mrow = n0 + wave * 32 + mt * 16 + quad * 4;
#pragma unroll
        for (int r = 0; r < 4; r++) {
            int n = mrow + r;
            if (n < N_NODES) {
#pragma unroll
                for (int nt = 0; nt < 8; nt++)
                    out[(long)n * HID + nt * 16 + l16] = acc[mt][nt][r];
            }
        }
    }
}

// ---------------------------------------------------------------------------
// MFMA GEMM 2: out = Basis(h) @ Cmat   [N x 512]@[512 x 128], basis on the fly
// k = i*4 + d; per K-tile of 32 -> 8 h-features. Same MFMA micro-structure.
// ---------------------------------------------------------------------------
__global__ __launch_bounds__(256, 3) void cheb_gemm(const float* __restrict__ h,
                                                    const float* __restrict__ Cmat,
                                                    float* __restrict__ out) {
    __shared__ __align__(16) short As[128][40];
    __shared__ __align__(16) short Bs[128][40];
    const int tid  = threadIdx.x;
    const int lane = tid & 63;
    const int wave = tid >> 6;
    const int quad = lane >> 4;
    const int l16  = lane & 15;
    const int n0   = blockIdx.x * 128;
    const int lr   = tid >> 1;
    const int lh   = tid & 1;

    f32x4 acc[2][8];
#pragma unroll
    for (int mt = 0; mt < 2; mt++)
#pragma unroll
        for (int nt = 0; nt < 8; nt++)
#pragma unroll
            for (int r = 0; r < 4; r++) acc[mt][nt][r] = 0.f;

    for (int kt = 0; kt < 16; kt++) {
        const int k0 = kt * 32;
        const int i0 = kt * 8;          // h-feature base
        // ---- A stage: 4 h-features per thread -> 16 bf16 basis values
        {
            int n = n0 + lr; if (n >= N_NODES) n = N_NODES - 1;
            const float4 hv = *(const float4*)(h + (long)n * HID + i0 + lh * 4);
            float hx[4] = {hv.x, hv.y, hv.z, hv.w};
            short tmp[16];
#pragma unroll
            for (int q = 0; q < 4; q++) {
                float xx = fminf(fmaxf(hx[q], -15.f), 15.f);
                float e  = __expf(2.f * xx);
                float t  = (e - 1.f) / (e + 1.f);     // tanh
                float T2 = 2.f * t * t - 1.f;
                float T3 = 2.f * t * T2 - t;
                tmp[q * 4 + 0] = (short)0x3F80;       // bf16(1.0)
                tmp[q * 4 + 1] = f2bf(t);
                tmp[q * 4 + 2] = f2bf(T2);
                tmp[q * 4 + 3] = f2bf(T3);
            }
            *(bf16x8*)&As[lr][lh * 16]     = *(bf16x8*)&tmp[0];
            *(bf16x8*)&As[lr][lh * 16 + 8] = *(bf16x8*)&tmp[8];
        }
        // ---- B stage: Cmat[k0+kk][n] -> Bs[n][kk]
        for (int idx = tid; idx < 32 * 128; idx += 256) {
            int kk = idx >> 7;
            int m  = idx & 127;
            Bs[m][kk] = f2bf(Cmat[(k0 + kk) * HID + m]);
        }
        __syncthreads();
        bf16x8 a0 = *(const bf16x8*)&As[wave * 32 + l16][quad * 8];
        bf16x8 a1 = *(const bf16x8*)&As[wave * 32 + 16 + l16][quad * 8];
#pragma unroll
        for (int nt = 0; nt < 8; nt++) {
            bf16x8 b = *(const bf16x8*)&Bs[nt * 16 + l16][quad * 8];
            acc[0][nt] = __builtin_amdgcn_mfma_f32_16x16x32_bf16(a0, b, acc[0][nt], 0, 0, 0);
            acc[1][nt] = __builtin_amdgcn_mfma_f32_16x16x32_bf16(a1, b, acc[1][nt], 0, 0, 0);
        }
        __syncthreads();
    }
#pragma unroll
    for (int mt = 0; mt < 2; mt++) {
        int mrow = n0 + wave * 32 + mt * 16 + quad * 4;
#pragma unroll
        for (int r = 0; r < 4; r++) {
            int n = mrow + r;
            if (n < N_NODES) {
#pragma unroll
                for (int nt = 0; nt < 8; nt++)
                    out[(long)n * HID + nt * 16 + l16] = acc[mt][nt][r];
            }
        }
    }
}

// ---------------------------------------------------------------------------
// SpMM gather: out[row][:] = sum over CSR range of h[col][:]
// one wave per row, float2 per lane (64 lanes * 8B = 512B row)
// ---------------------------------------------------------------------------
__global__ __launch_bounds__(256) void spmm_gather(const int* __restrict__ row_start,
                                                   const int* __restrict__ col_sorted,
                                                   const float* __restrict__ h,
                                                   float* __restrict__ out) {
    const int wid  = (blockIdx.x * 256 + threadIdx.x) >> 6;
    const int lane = threadIdx.x & 63;
    if (wid >= N_NODES) return;
    const int s = row_start[wid];
    const int e = row_start[wid + 1];
    const float2* __restrict__ h2 = (const float2*)h;
    float2 acc0 = {0.f, 0.f}, acc1 = {0.f, 0.f};
    int j = s;
    for (; j + 1 < e; j += 2) {
        int c0 = col_sorted[j];
        int c1 = col_sorted[j + 1];
        float2 v0 = h2[c0 * 64 + lane];
        float2 v1 = h2[c1 * 64 + lane];
        acc0.x += v0.x; acc0.y += v0.y;
        acc1.x += v1.x; acc1.y += v1.y;
    }
    if (j < e) {
        int c = col_sorted[j];
        float2 v = h2[c * 64 + lane];
        acc0.x += v.x; acc0.y += v.y;
    }
    acc0.x += acc1.x; acc0.y += acc1.y;
    ((float2*)out)[wid * 64 + lane] = acc0;
}

// ---------------------------------------------------------------------------
// Output GEMM (128->16) + log_softmax, fused. 16 nodes/block, 16 thr/node.
// ---------------------------------------------------------------------------
__global__ __launch_bounds__(256) void out_kernel(const float* __restrict__ h,
                                                  const float* __restrict__ Wo,
                                                  float* __restrict__ out) {
    __shared__ float Ws[HID * 16];
    __shared__ float Hs[16][HID];
    const int tid = threadIdx.x;
    const int n0 = blockIdx.x * 16;
    for (int idx = tid; idx < HID * 16; idx += 256) Ws[idx] = Wo[idx];
    for (int idx = tid; idx < 16 * HID; idx += 256) {
        int nl = idx >> 7;
        int k  = idx & 127;
        Hs[nl][k] = h[(n0 + nl) * HID + k];
    }
    __syncthreads();
    const int nl = tid >> 4;
    const int o  = tid & 15;
    float acc = 0.f;
#pragma unroll
    for (int k = 0; k < HID; k++) acc += Hs[nl][k] * Ws[k * 16 + o];
    float mx = acc;
#pragma unroll
    for (int m = 8; m >= 1; m >>= 1) mx = fmaxf(mx, __shfl_xor(mx, m));
    float ex = expf(acc - mx);
    float se = ex;
#pragma unroll
    for (int m = 8; m >= 1; m >>= 1) se += __shfl_xor(se, m);
    out[(n0 + nl) * 16 + o] = acc - mx - logf(se);
}

// ---------------------------------------------------------------------------

extern "C" void kernel_launch(void* const* d_in, const int* in_sizes, int n_in,
                              void* d_out, int out_size, void* d_ws, size_t ws_size,
                              hipStream_t stream) {
    const float* x     = (const float*)d_in[0];
    const int*   ei    = (const int*)d_in[1];
    const float* W_in  = (const float*)d_in[2];
    const float* cheb  = (const float*)d_in[3];
    const float* W_out = (const float*)d_in[4];
    float* out = (float*)d_out;

    char* p = (char*)d_ws;
    float* hA        = (float*)p; p += (size_t)N_NODES * HID * 4;     // 51.2 MB
    float* hB        = (float*)p; p += (size_t)N_NODES * HID * 4;     // 51.2 MB
    int*   col_sorted= (int*)p;   p += (size_t)N_EDGES * 4;           // 6.4 MB
    float* Cmat      = (float*)p; p += (size_t)2 * KDIM * HID * 4;    // 0.5 MB
    int*   counts    = (int*)p;   p += (size_t)N_NODES * 4;
    int*   row_start = (int*)p;   p += (size_t)(N_NODES + 1) * 4;
    int*   cursor    = (int*)p;   p += (size_t)N_NODES * 4;

    const int nblk_gemm = (N_NODES + 127) / 128;       // 782
    const int nblk_edge = N_EDGES / 256;               // 6250
    const int nblk_spmm = (N_NODES + 3) / 4;           // 25000
    const int nblk_out  = N_NODES / 16;                // 6250

    hipMemsetAsync(counts, 0, (size_t)N_NODES * 4, stream);
    hist_kernel<<<nblk_edge, 256, 0, stream>>>(ei, counts);
    scan_kernel<<<1, 1024, 0, stream>>>(counts, row_start, cursor);
    scatter_kernel<<<nblk_edge, 256, 0, stream>>>(ei, cursor, col_sorted);
    repack_kernel<<<2 * KDIM * HID / 256, 256, 0, stream>>>(cheb, Cmat);

    gemm_xw<<<nblk_gemm, 256, 0, stream>>>(x, W_in, hA);
    spmm_gather<<<nblk_spmm, 256, 0, stream>>>(row_start, col_sorted, hA, hB);

    cheb_gemm<<<nblk_gemm, 256, 0, stream>>>(hB, Cmat, hA);               // layer 0
    spmm_gather<<<nblk_spmm, 256, 0, stream>>>(row_start, col_sorted, hA, hB);

    cheb_gemm<<<nblk_gemm, 256, 0, stream>>>(hB, Cmat + KDIM * HID, hA);  // layer 1
    spmm_gather<<<nblk_spmm, 256, 0, stream>>>(row_start, col_sorted, hA, hB);

    out_kernel<<<nblk_out, 256, 0, stream>>>(hB, W_out, out);
}

// Round 3
// 902.303 us; speedup vs baseline: 2.6126x; 1.5957x over previous
//
#include <hip/hip_runtime.h>
#include <hip/hip_bf16.h>

#define N_NODES 100000
#define N_EDGES 1600000
#define IN_DIM  500
#define HID     128
#define KDIM    512   // HID * (DEG+1)
#define NCH     98    // ceil(N_NODES/1024) scan chunks

typedef __attribute__((ext_vector_type(8))) short bf16x8;
typedef __attribute__((ext_vector_type(4))) float f32x4;

__device__ inline short f2bf(float x) {
    union { float f; unsigned u; } v; v.f = x;
    unsigned r = (v.u + 0x7FFFu + ((v.u >> 16) & 1u)) >> 16;  // RNE
    return (short)r;
}
__device__ inline float bf_lo(unsigned u) { union { unsigned u; float f; } v; v.u = u << 16; return v.f; }
__device__ inline float bf_hi(unsigned u) { union { unsigned u; float f; } v; v.u = u & 0xFFFF0000u; return v.f; }
__device__ inline float bf2f(unsigned short s) { union { unsigned u; float f; } v; v.u = ((unsigned)s) << 16; return v.f; }

// ---------------------------------------------------------------------------
// CSR build: histogram -> 3-stage parallel scan -> scatter
// ---------------------------------------------------------------------------

__global__ __launch_bounds__(256) void hist_kernel(const int* __restrict__ ei,
                                                   int* __restrict__ counts) {
    int e = blockIdx.x * 256 + threadIdx.x;
    if (e < N_EDGES) atomicAdd(&counts[ei[e]], 1);
}

// stage 1: per-1024-chunk sums (98 blocks x 256 thr)
__global__ __launch_bounds__(256) void chunk_sum_kernel(const int* __restrict__ counts,
                                                        int* __restrict__ csum) {
    const int b = blockIdx.x, tid = threadIdx.x;
    int s = 0;
#pragma unroll
    for (int q = 0; q < 4; q++) {
        int i = b * 1024 + q * 256 + tid;
        if (i < N_NODES) s += counts[i];
    }
#pragma unroll
    for (int m = 32; m >= 1; m >>= 1) s += __shfl_xor(s, m);
    __shared__ int ws[4];
    if ((tid & 63) == 0) ws[tid >> 6] = s;
    __syncthreads();
    if (tid == 0) csum[b] = ws[0] + ws[1] + ws[2] + ws[3];
}

// stage 2: exclusive scan of the 98 chunk sums (1 tiny block)
__global__ __launch_bounds__(128) void scan_top_kernel(const int* __restrict__ csum,
                                                       int* __restrict__ coff) {
    __shared__ int buf[128];
    const int tid = threadIdx.x;
    int v = (tid < NCH) ? csum[tid] : 0;
    buf[tid] = v;
    __syncthreads();
    for (int off = 1; off < 128; off <<= 1) {
        int t = (tid >= off) ? buf[tid - off] : 0;
        __syncthreads();
        buf[tid] += t;
        __syncthreads();
    }
    if (tid < NCH) coff[tid] = buf[tid] - v;
}

// stage 3: per-chunk LDS scan + chunk offset -> row_start, cursor (98 x 1024)
__global__ __launch_bounds__(1024) void scan_within_kernel(const int* __restrict__ counts,
                                                           const int* __restrict__ coff,
                                                           int* __restrict__ row_start,
                                                           int* __restrict__ cursor) {
    __shared__ int buf[1024];
    const int b = blockIdx.x, tid = threadIdx.x;
    const int i = b * 1024 + tid;
    int v = (i < N_NODES) ? counts[i] : 0;
    buf[tid] = v;
    __syncthreads();
    for (int off = 1; off < 1024; off <<= 1) {
        int t = (tid >= off) ? buf[tid - off] : 0;
        __syncthreads();
        buf[tid] += t;
        __syncthreads();
    }
    int excl = buf[tid] - v + coff[b];
    if (i < N_NODES) {
        row_start[i] = excl;
        cursor[i]    = excl;
        if (i == N_NODES - 1) row_start[N_NODES] = excl + v;
    }
}

__global__ __launch_bounds__(256) void scatter_kernel(const int* __restrict__ ei,
                                                      int* __restrict__ cursor,
                                                      int* __restrict__ col_sorted) {
    int e = blockIdx.x * 256 + threadIdx.x;
    if (e < N_EDGES) {
        int r = ei[e];
        int c = ei[N_EDGES + e];
        int pos = atomicAdd(&cursor[r], 1);
        col_sorted[pos] = c;
    }
}

// ---------------------------------------------------------------------------
// Weight repacks (once per launch): bf16, transposed to [n][k] GEMM-B layout
// ---------------------------------------------------------------------------
// cheb[l][i][o][d] -> Bmat[l][o][k=i*4+d] bf16
__global__ __launch_bounds__(256) void repack_cheb(const float* __restrict__ cheb,
                                                   unsigned short* __restrict__ Bmat) {
    int idx = blockIdx.x * 256 + threadIdx.x;   // < 2*128*512
    int l = idx >> 16;
    int rem = idx & 65535;
    int o = rem >> 9;         // 0..127
    int k = rem & 511;        // 0..511
    int i = k >> 2;
    int d = k & 3;
    Bmat[idx] = (unsigned short)f2bf(cheb[l * 65536 + i * 512 + o * 4 + d]);
}
// W_in[k][o] (500x128) -> Wmat[o][k] bf16, zero-padded to k<512
__global__ __launch_bounds__(256) void repack_w(const float* __restrict__ W,
                                                unsigned short* __restrict__ Wmat) {
    int idx = blockIdx.x * 256 + threadIdx.x;   // < 128*512
    int o = idx >> 9;
    int k = idx & 511;
    Wmat[idx] = (k < IN_DIM) ? (unsigned short)f2bf(W[k * HID + o]) : 0;
}

// ---------------------------------------------------------------------------
// MFMA GEMM 1: h = x @ W_in  [100000 x 500(512)] @ [500 x 128] -> bf16 out
// ---------------------------------------------------------------------------
__global__ __launch_bounds__(256, 3) void gemm_xw(const float* __restrict__ x,
                                                  const unsigned short* __restrict__ Wmat,
                                                  unsigned short* __restrict__ out) {
    __shared__ __align__(16) short As[128][40];   // [m][k] bf16, row 80 B
    __shared__ __align__(16) short Bs[128][40];   // [n][k] bf16
    const int tid  = threadIdx.x;
    const int lane = tid & 63;
    const int wave = tid >> 6;
    const int quad = lane >> 4;
    const int l16  = lane & 15;
    const int n0   = blockIdx.x * 128;
    const int lr   = tid >> 1;
    const int lh   = tid & 1;

    f32x4 acc[2][8];
#pragma unroll
    for (int mt = 0; mt < 2; mt++)
#pragma unroll
        for (int nt = 0; nt < 8; nt++)
#pragma unroll
            for (int r = 0; r < 4; r++) acc[mt][nt][r] = 0.f;

    for (int kt = 0; kt < 16; kt++) {
        const int k0 = kt * 32;
        // A stage: x[n0+lr][k0+lh*16 .. +15] f32 -> bf16
        {
            int n = n0 + lr; if (n >= N_NODES) n = N_NODES - 1;
            const float* src = x + (long)n * IN_DIM + k0 + lh * 16;
            const int kb = k0 + lh * 16;
            float v[16];
            if (kb + 16 <= IN_DIM) {
                const float4* s4 = (const float4*)src;
                float4 a0 = s4[0], a1 = s4[1], a2 = s4[2], a3 = s4[3];
                v[0]=a0.x; v[1]=a0.y; v[2]=a0.z; v[3]=a0.w;
                v[4]=a1.x; v[5]=a1.y; v[6]=a1.z; v[7]=a1.w;
                v[8]=a2.x; v[9]=a2.y; v[10]=a2.z; v[11]=a2.w;
                v[12]=a3.x; v[13]=a3.y; v[14]=a3.z; v[15]=a3.w;
            } else {
#pragma unroll
                for (int q = 0; q < 16; q++) v[q] = (kb + q < IN_DIM) ? src[q] : 0.f;
            }
            short tmp[16];
#pragma unroll
            for (int q = 0; q < 16; q++) tmp[q] = f2bf(v[q]);
            *(bf16x8*)&As[lr][lh * 16]     = *(bf16x8*)&tmp[0];
            *(bf16x8*)&As[lr][lh * 16 + 8] = *(bf16x8*)&tmp[8];
        }
        // B stage: pure ushort8 copies from prepacked Wmat[o][k]
        for (int idx = tid; idx < 512; idx += 256) {
            int m = idx >> 2, kq = idx & 3;
            *(bf16x8*)&Bs[m][kq * 8] = *(const bf16x8*)&Wmat[m * 512 + k0 + kq * 8];
        }
        __syncthreads();
        bf16x8 a0 = *(const bf16x8*)&As[wave * 32 + l16][quad * 8];
        bf16x8 a1 = *(const bf16x8*)&As[wave * 32 + 16 + l16][quad * 8];
#pragma unroll
        for (int nt = 0; nt < 8; nt++) {
            bf16x8 b = *(const bf16x8*)&Bs[nt * 16 + l16][quad * 8];
            acc[0][nt] = __builtin_amdgcn_mfma_f32_16x16x32_bf16(a0, b, acc[0][nt], 0, 0, 0);
            acc[1][nt] = __builtin_amdgcn_mfma_f32_16x16x32_bf16(a1, b, acc[1][nt], 0, 0, 0);
        }
        __syncthreads();
    }
#pragma unroll
    for (int mt = 0; mt < 2; mt++) {
        int mrow = n0 + wave * 32 + mt * 16 + quad * 4;
#pragma unroll
        for (int r = 0; r < 4; r++) {
            int n = mrow + r;
            if (n < N_NODES) {
#pragma unroll
                for (int nt = 0; nt < 8; nt++)
                    out[(long)n * HID + nt * 16 + l16] = (unsigned short)f2bf(acc[mt][nt][r]);
            }
        }
    }
}

// ---------------------------------------------------------------------------
// MFMA GEMM 2: out = Basis(h) @ C  [N x 512]@[512 x 128], h bf16, out bf16
// ---------------------------------------------------------------------------
__global__ __launch_bounds__(256, 3) void cheb_gemm(const unsigned short* __restrict__ h,
                                                    const unsigned short* __restrict__ Bmat,
                                                    unsigned short* __restrict__ out) {
    __shared__ __align__(16) short As[128][40];
    __shared__ __align__(16) short Bs[128][40];
    const int tid  = threadIdx.x;
    const int lane = tid & 63;
    const int wave = tid >> 6;
    const int quad = lane >> 4;
    const int l16  = lane & 15;
    const int n0   = blockIdx.x * 128;
    const int lr   = tid >> 1;
    const int lh   = tid & 1;

    f32x4 acc[2][8];
#pragma unroll
    for (int mt = 0; mt < 2; mt++)
#pragma unroll
        for (int nt = 0; nt < 8; nt++)
#pragma unroll
            for (int r = 0; r < 4; r++) acc[mt][nt][r] = 0.f;

    for (int kt = 0; kt < 16; kt++) {
        const int k0 = kt * 32;
        const int i0 = kt * 8;
        // A stage: 4 bf16 h-features -> 16 bf16 basis values
        {
            int n = n0 + lr; if (n >= N_NODES) n = N_NODES - 1;
            const ushort4 hv = *(const ushort4*)(h + (long)n * HID + i0 + lh * 4);
            float hx[4] = {bf2f(hv.x), bf2f(hv.y), bf2f(hv.z), bf2f(hv.w)};
            short tmp[16];
#pragma unroll
            for (int q = 0; q < 4; q++) {
                float xx = fminf(fmaxf(hx[q], -15.f), 15.f);
                float e  = __expf(2.f * xx);
                float t  = (e - 1.f) / (e + 1.f);     // tanh
                float T2 = 2.f * t * t - 1.f;
                float T3 = 2.f * t * T2 - t;
                tmp[q * 4 + 0] = (short)0x3F80;       // bf16(1.0)
                tmp[q * 4 + 1] = f2bf(t);
                tmp[q * 4 + 2] = f2bf(T2);
                tmp[q * 4 + 3] = f2bf(T3);
            }
            *(bf16x8*)&As[lr][lh * 16]     = *(bf16x8*)&tmp[0];
            *(bf16x8*)&As[lr][lh * 16 + 8] = *(bf16x8*)&tmp[8];
        }
        // B stage: pure ushort8 copies from prepacked Bmat[o][k]
        for (int idx = tid; idx < 512; idx += 256) {
            int m = idx >> 2, kq = idx & 3;
            *(bf16x8*)&Bs[m][kq * 8] = *(const bf16x8*)&Bmat[m * 512 + k0 + kq * 8];
        }
        __syncthreads();
        bf16x8 a0 = *(const bf16x8*)&As[wave * 32 + l16][quad * 8];
        bf16x8 a1 = *(const bf16x8*)&As[wave * 32 + 16 + l16][quad * 8];
#pragma unroll
        for (int nt = 0; nt < 8; nt++) {
            bf16x8 b = *(const bf16x8*)&Bs[nt * 16 + l16][quad * 8];
            acc[0][nt] = __builtin_amdgcn_mfma_f32_16x16x32_bf16(a0, b, acc[0][nt], 0, 0, 0);
            acc[1][nt] = __builtin_amdgcn_mfma_f32_16x16x32_bf16(a1, b, acc[1][nt], 0, 0, 0);
        }
        __syncthreads();
    }
#pragma unroll
    for (int mt = 0; mt < 2; mt++) {
        int mrow = n0 + wave * 32 + mt * 16 + quad * 4;
#pragma unroll
        for (int r = 0; r < 4; r++) {
            int n = mrow + r;
            if (n < N_NODES) {
#pragma unroll
                for (int nt = 0; nt < 8; nt++)
                    out[(long)n * HID + nt * 16 + l16] = (unsigned short)f2bf(acc[mt][nt][r]);
            }
        }
    }
}

// ---------------------------------------------------------------------------
// SpMM gather (bf16): out[row] = sum_cols h[col]; wave/row, uint (2xbf16)/lane
// row = 64 lanes * 4 B = 256 B coalesced; accumulate f32, store bf16.
// ---------------------------------------------------------------------------
__global__ __launch_bounds__(256) void spmm_gather(const int* __restrict__ row_start,
                                                   const int* __restrict__ col_sorted,
                                                   const unsigned short* __restrict__ h,
                                                   unsigned short* __restrict__ out) {
    const int wid  = (blockIdx.x * 256 + threadIdx.x) >> 6;
    const int lane = threadIdx.x & 63;
    if (wid >= N_NODES) return;
    const int s = row_start[wid];
    const int e = row_start[wid + 1];
    const unsigned* __restrict__ h1 = (const unsigned*)h;
    float ax0 = 0.f, ay0 = 0.f, ax1 = 0.f, ay1 = 0.f;
    int j = s;
    for (; j + 1 < e; j += 2) {
        int c0 = col_sorted[j];
        int c1 = col_sorted[j + 1];
        unsigned u0 = h1[c0 * 64 + lane];
        unsigned u1 = h1[c1 * 64 + lane];
        ax0 += bf_lo(u0); ay0 += bf_hi(u0);
        ax1 += bf_lo(u1); ay1 += bf_hi(u1);
    }
    if (j < e) {
        unsigned u = h1[col_sorted[j] * 64 + lane];
        ax0 += bf_lo(u); ay0 += bf_hi(u);
    }
    ax0 += ax1; ay0 += ay1;
    unsigned lo = (unsigned)(unsigned short)f2bf(ax0);
    unsigned hi = (unsigned)(unsigned short)f2bf(ay0);
    ((unsigned*)out)[wid * 64 + lane] = lo | (hi << 16);
}

// ---------------------------------------------------------------------------
// Output GEMM (128->16) + log_softmax, fused. h bf16 in, f32 out.
// ---------------------------------------------------------------------------
__global__ __launch_bounds__(256) void out_kernel(const unsigned short* __restrict__ h,
                                                  const float* __restrict__ Wo,
                                                  float* __restrict__ out) {
    __shared__ float Ws[HID * 16];
    __shared__ float Hs[16][HID];
    const int tid = threadIdx.x;
    const int n0 = blockIdx.x * 16;
    for (int idx = tid; idx < HID * 16; idx += 256) Ws[idx] = Wo[idx];
    const unsigned* h1 = (const unsigned*)h;
    for (int idx = tid; idx < 16 * 64; idx += 256) {
        int nl = idx >> 6;
        int kp = idx & 63;
        unsigned u = h1[(n0 + nl) * 64 + kp];
        Hs[nl][kp * 2]     = bf_lo(u);
        Hs[nl][kp * 2 + 1] = bf_hi(u);
    }
    __syncthreads();
    const int nl = tid >> 4;
    const int o  = tid & 15;
    float acc = 0.f;
#pragma unroll
    for (int k = 0; k < HID; k++) acc += Hs[nl][k] * Ws[k * 16 + o];
    float mx = acc;
#pragma unroll
    for (int m = 8; m >= 1; m >>= 1) mx = fmaxf(mx, __shfl_xor(mx, m));
    float ex = expf(acc - mx);
    float se = ex;
#pragma unroll
    for (int m = 8; m >= 1; m >>= 1) se += __shfl_xor(se, m);
    out[(n0 + nl) * 16 + o] = acc - mx - logf(se);
}

// ---------------------------------------------------------------------------

extern "C" void kernel_launch(void* const* d_in, const int* in_sizes, int n_in,
                              void* d_out, int out_size, void* d_ws, size_t ws_size,
                              hipStream_t stream) {
    const float* x     = (const float*)d_in[0];
    const int*   ei    = (const int*)d_in[1];
    const float* W_in  = (const float*)d_in[2];
    const float* cheb  = (const float*)d_in[3];
    const float* W_out = (const float*)d_in[4];
    float* out = (float*)d_out;

    char* p = (char*)d_ws;
    unsigned short* hA   = (unsigned short*)p; p += (size_t)N_NODES * HID * 2;   // 25.6 MB
    unsigned short* hB   = (unsigned short*)p; p += (size_t)N_NODES * HID * 2;   // 25.6 MB
    int*   col_sorted    = (int*)p;            p += (size_t)N_EDGES * 4;         // 6.4 MB
    unsigned short* Bmat = (unsigned short*)p; p += (size_t)2 * HID * KDIM * 2;  // 256 KB
    unsigned short* Wmat = (unsigned short*)p; p += (size_t)HID * KDIM * 2;      // 128 KB
    int*   counts        = (int*)p;            p += (size_t)N_NODES * 4;
    int*   row_start     = (int*)p;            p += (size_t)(N_NODES + 1) * 4;
    int*   cursor        = (int*)p;            p += (size_t)N_NODES * 4;
    int*   csum          = (int*)p;            p += (size_t)NCH * 4;
    int*   coff          = (int*)p;            p += (size_t)NCH * 4;

    const int nblk_gemm = (N_NODES + 127) / 128;       // 782
    const int nblk_edge = N_EDGES / 256;               // 6250
    const int nblk_spmm = (N_NODES + 3) / 4;           // 25000
    const int nblk_out  = N_NODES / 16;                // 6250

    hipMemsetAsync(counts, 0, (size_t)N_NODES * 4, stream);
    hist_kernel<<<nblk_edge, 256, 0, stream>>>(ei, counts);
    chunk_sum_kernel<<<NCH, 256, 0, stream>>>(counts, csum);
    scan_top_kernel<<<1, 128, 0, stream>>>(csum, coff);
    scan_within_kernel<<<NCH, 1024, 0, stream>>>(counts, coff, row_start, cursor);
    scatter_kernel<<<nblk_edge, 256, 0, stream>>>(ei, cursor, col_sorted);
    repack_cheb<<<2 * HID * KDIM / 256, 256, 0, stream>>>(cheb, Bmat);
    repack_w<<<HID * KDIM / 256, 256, 0, stream>>>(W_in, Wmat);

    gemm_xw<<<nblk_gemm, 256, 0, stream>>>(x, Wmat, hA);
    spmm_gather<<<nblk_spmm, 256, 0, stream>>>(row_start, col_sorted, hA, hB);

    cheb_gemm<<<nblk_gemm, 256, 0, stream>>>(hB, Bmat, hA);                    // layer 0
    spmm_gather<<<nblk_spmm, 256, 0, stream>>>(row_start, col_sorted, hA, hB);

    cheb_gemm<<<nblk_gemm, 256, 0, stream>>>(hB, Bmat + HID * KDIM, hA);       // layer 1
    spmm_gather<<<nblk_spmm, 256, 0, stream>>>(row_start, col_sorted, hA, hB);

    out_kernel<<<nblk_out, 256, 0, stream>>>(hB, W_out, out);
}

// Round 4
// 740.856 us; speedup vs baseline: 3.1819x; 1.2179x over previous
//
#include <hip/hip_runtime.h>
#include <hip/hip_bf16.h>

#define N_NODES 100000
#define N_EDGES 1600000
#define IN_DIM  500
#define HID     128
#define KDIM    512   // HID * (DEG+1)
#define NB      782   // ceil(N_NODES/128) buckets
#define BCAP    4096  // bucket capacity (expected 2046, >20 sigma headroom)

typedef __attribute__((ext_vector_type(8))) short bf16x8;
typedef __attribute__((ext_vector_type(4))) float f32x4;

__device__ inline short f2bf(float x) {
    union { float f; unsigned u; } v; v.f = x;
    unsigned r = (v.u + 0x7FFFu + ((v.u >> 16) & 1u)) >> 16;  // RNE
    return (short)r;
}
__device__ inline float bf_lo(unsigned u) { union { unsigned u; float f; } v; v.u = u << 16; return v.f; }
__device__ inline float bf_hi(unsigned u) { union { unsigned u; float f; } v; v.u = u & 0xFFFF0000u; return v.f; }
__device__ inline float bf2f(unsigned short s) { union { unsigned u; float f; } v; v.u = ((unsigned)s) << 16; return v.f; }

// ---------------------------------------------------------------------------
// CSR build, two-pass binned:
//   bin:   edge -> bucket append (packed (r&127)<<17 | c), bucket = r>>7
//   bscan: exclusive scan of 782 bucket counts
//   place: per-bucket LDS hist + scan -> row_start + col_sorted (compact writes)
// ---------------------------------------------------------------------------

__global__ __launch_bounds__(256) void bin_kernel(const int* __restrict__ ei,
                                                  int* __restrict__ bcnt,
                                                  unsigned* __restrict__ buf) {
    int e = blockIdx.x * 256 + threadIdx.x;
    if (e < N_EDGES) {
        int r = ei[e];
        int c = ei[N_EDGES + e];
        int b = r >> 7;
        int p = atomicAdd(&bcnt[b * 16], 1);   // stride 64 B: spread L2 slices
        if (p < BCAP) buf[b * BCAP + p] = ((unsigned)(r & 127) << 17) | (unsigned)c;
    }
}

__global__ __launch_bounds__(1024) void bscan_kernel(const int* __restrict__ bcnt,
                                                     int* __restrict__ bbase) {
    __shared__ int buf[1024];
    const int tid = threadIdx.x;
    int v = (tid < NB) ? bcnt[tid * 16] : 0;
    buf[tid] = v;
    __syncthreads();
    for (int off = 1; off < 1024; off <<= 1) {
        int t = (tid >= off) ? buf[tid - off] : 0;
        __syncthreads();
        buf[tid] += t;
        __syncthreads();
    }
    if (tid < NB) bbase[tid] = buf[tid] - v;   // exclusive
}

__global__ __launch_bounds__(256) void place_kernel(const unsigned* __restrict__ buf,
                                                    const int* __restrict__ bcnt,
                                                    const int* __restrict__ bbase,
                                                    int* __restrict__ row_start,
                                                    int* __restrict__ col_sorted) {
    __shared__ int hist[128];
    __shared__ int scan[128];
    __shared__ int cur[128];
    const int b = blockIdx.x, tid = threadIdx.x;
    int cnt = bcnt[b * 16]; if (cnt > BCAP) cnt = BCAP;
    const int base = bbase[b];
    if (tid < 128) hist[tid] = 0;
    __syncthreads();
    for (int i = tid; i < cnt; i += 256)
        atomicAdd(&hist[buf[b * BCAP + i] >> 17], 1);
    __syncthreads();
    if (tid < 128) scan[tid] = hist[tid];
    __syncthreads();
    for (int off = 1; off < 128; off <<= 1) {
        int t = (tid < 128 && tid >= off) ? scan[tid - off] : 0;
        __syncthreads();
        if (tid < 128) scan[tid] += t;
        __syncthreads();
    }
    if (tid < 128) {
        int excl = scan[tid] - hist[tid] + base;
        cur[tid] = excl;
        int r = b * 128 + tid;
        if (r < N_NODES) row_start[r] = excl;
        if (r == N_NODES - 1) row_start[N_NODES] = excl + hist[tid];
    }
    __syncthreads();
    for (int i = tid; i < cnt; i += 256) {
        unsigned u = buf[b * BCAP + i];
        int rl = (int)(u >> 17);
        int c  = (int)(u & 0x1FFFFu);
        int pos = atomicAdd(&cur[rl], 1);
        col_sorted[pos] = c;
    }
}

// ---------------------------------------------------------------------------
// Weight repacks (once per launch): bf16, transposed to [n][k] GEMM-B layout
// ---------------------------------------------------------------------------
__global__ __launch_bounds__(256) void repack_cheb(const float* __restrict__ cheb,
                                                   unsigned short* __restrict__ Bmat) {
    int idx = blockIdx.x * 256 + threadIdx.x;   // < 2*128*512
    int l = idx >> 16;
    int rem = idx & 65535;
    int o = rem >> 9;
    int k = rem & 511;
    int i = k >> 2;
    int d = k & 3;
    Bmat[idx] = (unsigned short)f2bf(cheb[l * 65536 + i * 512 + o * 4 + d]);
}
__global__ __launch_bounds__(256) void repack_w(const float* __restrict__ W,
                                                unsigned short* __restrict__ Wmat) {
    int idx = blockIdx.x * 256 + threadIdx.x;   // < 128*512
    int o = idx >> 9;
    int k = idx & 511;
    Wmat[idx] = (k < IN_DIM) ? (unsigned short)f2bf(W[k * HID + o]) : 0;
}

// ---------------------------------------------------------------------------
// MFMA GEMM 1: h = x @ W_in  [100000 x 500(512)] @ [500 x 128] -> bf16 out
// ---------------------------------------------------------------------------
__global__ __launch_bounds__(256, 3) void gemm_xw(const float* __restrict__ x,
                                                  const unsigned short* __restrict__ Wmat,
                                                  unsigned short* __restrict__ out) {
    __shared__ __align__(16) short As[128][40];
    __shared__ __align__(16) short Bs[128][40];
    const int tid  = threadIdx.x;
    const int lane = tid & 63;
    const int wave = tid >> 6;
    const int quad = lane >> 4;
    const int l16  = lane & 15;
    const int n0   = blockIdx.x * 128;
    const int lr   = tid >> 1;
    const int lh   = tid & 1;

    f32x4 acc[2][8];
#pragma unroll
    for (int mt = 0; mt < 2; mt++)
#pragma unroll
        for (int nt = 0; nt < 8; nt++)
#pragma unroll
            for (int r = 0; r < 4; r++) acc[mt][nt][r] = 0.f;

    for (int kt = 0; kt < 16; kt++) {
        const int k0 = kt * 32;
        {
            int n = n0 + lr; if (n >= N_NODES) n = N_NODES - 1;
            const float* src = x + (long)n * IN_DIM + k0 + lh * 16;
            const int kb = k0 + lh * 16;
            float v[16];
            if (kb + 16 <= IN_DIM) {
                const float4* s4 = (const float4*)src;
                float4 a0 = s4[0], a1 = s4[1], a2 = s4[2], a3 = s4[3];
                v[0]=a0.x; v[1]=a0.y; v[2]=a0.z; v[3]=a0.w;
                v[4]=a1.x; v[5]=a1.y; v[6]=a1.z; v[7]=a1.w;
                v[8]=a2.x; v[9]=a2.y; v[10]=a2.z; v[11]=a2.w;
                v[12]=a3.x; v[13]=a3.y; v[14]=a3.z; v[15]=a3.w;
            } else {
#pragma unroll
                for (int q = 0; q < 16; q++) v[q] = (kb + q < IN_DIM) ? src[q] : 0.f;
            }
            short tmp[16];
#pragma unroll
            for (int q = 0; q < 16; q++) tmp[q] = f2bf(v[q]);
            *(bf16x8*)&As[lr][lh * 16]     = *(bf16x8*)&tmp[0];
            *(bf16x8*)&As[lr][lh * 16 + 8] = *(bf16x8*)&tmp[8];
        }
        for (int idx = tid; idx < 512; idx += 256) {
            int m = idx >> 2, kq = idx & 3;
            *(bf16x8*)&Bs[m][kq * 8] = *(const bf16x8*)&Wmat[m * 512 + k0 + kq * 8];
        }
        __syncthreads();
        bf16x8 a0 = *(const bf16x8*)&As[wave * 32 + l16][quad * 8];
        bf16x8 a1 = *(const bf16x8*)&As[wave * 32 + 16 + l16][quad * 8];
#pragma unroll
        for (int nt = 0; nt < 8; nt++) {
            bf16x8 b = *(const bf16x8*)&Bs[nt * 16 + l16][quad * 8];
            acc[0][nt] = __builtin_amdgcn_mfma_f32_16x16x32_bf16(a0, b, acc[0][nt], 0, 0, 0);
            acc[1][nt] = __builtin_amdgcn_mfma_f32_16x16x32_bf16(a1, b, acc[1][nt], 0, 0, 0);
        }
        __syncthreads();
    }
#pragma unroll
    for (int mt = 0; mt < 2; mt++) {
        int mrow = n0 + wave * 32 + mt * 16 + quad * 4;
#pragma unroll
        for (int r = 0; r < 4; r++) {
            int n = mrow + r;
            if (n < N_NODES) {
#pragma unroll
                for (int nt = 0; nt < 8; nt++)
                    out[(long)n * HID + nt * 16 + l16] = (unsigned short)f2bf(acc[mt][nt][r]);
            }
        }
    }
}

// ---------------------------------------------------------------------------
// MFMA GEMM 2: out = Basis(h) @ C  [N x 512]@[512 x 128], h bf16, out bf16
// ---------------------------------------------------------------------------
__global__ __launch_bounds__(256, 3) void cheb_gemm(const unsigned short* __restrict__ h,
                                                    const unsigned short* __restrict__ Bmat,
                                                    unsigned short* __restrict__ out) {
    __shared__ __align__(16) short As[128][40];
    __shared__ __align__(16) short Bs[128][40];
    const int tid  = threadIdx.x;
    const int lane = tid & 63;
    const int wave = tid >> 6;
    const int quad = lane >> 4;
    const int l16  = lane & 15;
    const int n0   = blockIdx.x * 128;
    const int lr   = tid >> 1;
    const int lh   = tid & 1;

    f32x4 acc[2][8];
#pragma unroll
    for (int mt = 0; mt < 2; mt++)
#pragma unroll
        for (int nt = 0; nt < 8; nt++)
#pragma unroll
            for (int r = 0; r < 4; r++) acc[mt][nt][r] = 0.f;

    for (int kt = 0; kt < 16; kt++) {
        const int k0 = kt * 32;
        const int i0 = kt * 8;
        {
            int n = n0 + lr; if (n >= N_NODES) n = N_NODES - 1;
            const ushort4 hv = *(const ushort4*)(h + (long)n * HID + i0 + lh * 4);
            float hx[4] = {bf2f(hv.x), bf2f(hv.y), bf2f(hv.z), bf2f(hv.w)};
            short tmp[16];
#pragma unroll
            for (int q = 0; q < 4; q++) {
                float xx = fminf(fmaxf(hx[q], -15.f), 15.f);
                float e  = __expf(2.f * xx);
                float t  = (e - 1.f) / (e + 1.f);     // tanh
                float T2 = 2.f * t * t - 1.f;
                float T3 = 2.f * t * T2 - t;
                tmp[q * 4 + 0] = (short)0x3F80;
                tmp[q * 4 + 1] = f2bf(t);
                tmp[q * 4 + 2] = f2bf(T2);
                tmp[q * 4 + 3] = f2bf(T3);
            }
            *(bf16x8*)&As[lr][lh * 16]     = *(bf16x8*)&tmp[0];
            *(bf16x8*)&As[lr][lh * 16 + 8] = *(bf16x8*)&tmp[8];
        }
        for (int idx = tid; idx < 512; idx += 256) {
            int m = idx >> 2, kq = idx & 3;
            *(bf16x8*)&Bs[m][kq * 8] = *(const bf16x8*)&Bmat[m * 512 + k0 + kq * 8];
        }
        __syncthreads();
        bf16x8 a0 = *(const bf16x8*)&As[wave * 32 + l16][quad * 8];
        bf16x8 a1 = *(const bf16x8*)&As[wave * 32 + 16 + l16][quad * 8];
#pragma unroll
        for (int nt = 0; nt < 8; nt++) {
            bf16x8 b = *(const bf16x8*)&Bs[nt * 16 + l16][quad * 8];
            acc[0][nt] = __builtin_amdgcn_mfma_f32_16x16x32_bf16(a0, b, acc[0][nt], 0, 0, 0);
            acc[1][nt] = __builtin_amdgcn_mfma_f32_16x16x32_bf16(a1, b, acc[1][nt], 0, 0, 0);
        }
        __syncthreads();
    }
#pragma unroll
    for (int mt = 0; mt < 2; mt++) {
        int mrow = n0 + wave * 32 + mt * 16 + quad * 4;
#pragma unroll
        for (int r = 0; r < 4; r++) {
            int n = mrow + r;
            if (n < N_NODES) {
#pragma unroll
                for (int nt = 0; nt < 8; nt++)
                    out[(long)n * HID + nt * 16 + l16] = (unsigned short)f2bf(acc[mt][nt][r]);
            }
        }
    }
}

// ---------------------------------------------------------------------------
// SpMM gather (bf16): wave/row, uint (2xbf16)/lane, 4-edge unroll for ILP
// ---------------------------------------------------------------------------
__global__ __launch_bounds__(256) void spmm_gather(const int* __restrict__ row_start,
                                                   const int* __restrict__ col_sorted,
                                                   const unsigned short* __restrict__ h,
                                                   unsigned short* __restrict__ out) {
    const int wid  = (blockIdx.x * 256 + threadIdx.x) >> 6;
    const int lane = threadIdx.x & 63;
    if (wid >= N_NODES) return;
    const int s = row_start[wid];
    const int e = row_start[wid + 1];
    const unsigned* __restrict__ h1 = (const unsigned*)h;
    float ax0 = 0.f, ay0 = 0.f, ax1 = 0.f, ay1 = 0.f;
    float ax2 = 0.f, ay2 = 0.f, ax3 = 0.f, ay3 = 0.f;
    int j = s;
    for (; j + 3 < e; j += 4) {
        int c0 = col_sorted[j];
        int c1 = col_sorted[j + 1];
        int c2 = col_sorted[j + 2];
        int c3 = col_sorted[j + 3];
        unsigned u0 = h1[c0 * 64 + lane];
        unsigned u1 = h1[c1 * 64 + lane];
        unsigned u2 = h1[c2 * 64 + lane];
        unsigned u3 = h1[c3 * 64 + lane];
        ax0 += bf_lo(u0); ay0 += bf_hi(u0);
        ax1 += bf_lo(u1); ay1 += bf_hi(u1);
        ax2 += bf_lo(u2); ay2 += bf_hi(u2);
        ax3 += bf_lo(u3); ay3 += bf_hi(u3);
    }
    for (; j < e; j++) {
        unsigned u = h1[col_sorted[j] * 64 + lane];
        ax0 += bf_lo(u); ay0 += bf_hi(u);
    }
    ax0 += ax1 + ax2 + ax3; ay0 += ay1 + ay2 + ay3;
    unsigned lo = (unsigned)(unsigned short)f2bf(ax0);
    unsigned hi = (unsigned)(unsigned short)f2bf(ay0);
    ((unsigned*)out)[wid * 64 + lane] = lo | (hi << 16);
}

// ---------------------------------------------------------------------------
// Output GEMM (128->16) + log_softmax, fused. h bf16 in, f32 out.
// ---------------------------------------------------------------------------
__global__ __launch_bounds__(256) void out_kernel(const unsigned short* __restrict__ h,
                                                  const float* __restrict__ Wo,
                                                  float* __restrict__ out) {
    __shared__ float Ws[HID * 16];
    __shared__ float Hs[16][HID];
    const int tid = threadIdx.x;
    const int n0 = blockIdx.x * 16;
    for (int idx = tid; idx < HID * 16; idx += 256) Ws[idx] = Wo[idx];
    const unsigned* h1 = (const unsigned*)h;
    for (int idx = tid; idx < 16 * 64; idx += 256) {
        int nl = idx >> 6;
        int kp = idx & 63;
        unsigned u = h1[(n0 + nl) * 64 + kp];
        Hs[nl][kp * 2]     = bf_lo(u);
        Hs[nl][kp * 2 + 1] = bf_hi(u);
    }
    __syncthreads();
    const int nl = tid >> 4;
    const int o  = tid & 15;
    float acc = 0.f;
#pragma unroll
    for (int k = 0; k < HID; k++) acc += Hs[nl][k] * Ws[k * 16 + o];
    float mx = acc;
#pragma unroll
    for (int m = 8; m >= 1; m >>= 1) mx = fmaxf(mx, __shfl_xor(mx, m));
    float ex = expf(acc - mx);
    float se = ex;
#pragma unroll
    for (int m = 8; m >= 1; m >>= 1) se += __shfl_xor(se, m);
    out[(n0 + nl) * 16 + o] = acc - mx - logf(se);
}

// ---------------------------------------------------------------------------

extern "C" void kernel_launch(void* const* d_in, const int* in_sizes, int n_in,
                              void* d_out, int out_size, void* d_ws, size_t ws_size,
                              hipStream_t stream) {
    const float* x     = (const float*)d_in[0];
    const int*   ei    = (const int*)d_in[1];
    const float* W_in  = (const float*)d_in[2];
    const float* cheb  = (const float*)d_in[3];
    const float* W_out = (const float*)d_in[4];
    float* out = (float*)d_out;

    char* p = (char*)d_ws;
    unsigned short* hA   = (unsigned short*)p; p += (size_t)N_NODES * HID * 2;   // 25.6 MB
    unsigned short* hB   = (unsigned short*)p; p += (size_t)N_NODES * HID * 2;   // 25.6 MB
    int*   col_sorted    = (int*)p;            p += (size_t)N_EDGES * 4;         // 6.4 MB
    unsigned short* Bmat = (unsigned short*)p; p += (size_t)2 * HID * KDIM * 2;  // 256 KB
    unsigned short* Wmat = (unsigned short*)p; p += (size_t)HID * KDIM * 2;      // 128 KB
    int*   row_start     = (int*)p;            p += (size_t)(N_NODES + 1) * 4;
    int*   bcnt          = (int*)p;            p += (size_t)NB * 16 * 4;         // 50 KB
    int*   bbase         = (int*)p;            p += (size_t)NB * 4;

    // bucket buffer aliases hA (dead until gemm_xw): 782*4096*4 = 12.8 MB < 25.6 MB
    unsigned* bbuf = (unsigned*)hA;

    const int nblk_gemm = (N_NODES + 127) / 128;       // 782
    const int nblk_edge = N_EDGES / 256;               // 6250
    const int nblk_spmm = (N_NODES + 3) / 4;           // 25000
    const int nblk_out  = N_NODES / 16;                // 6250

    hipMemsetAsync(bcnt, 0, (size_t)NB * 16 * 4, stream);
    bin_kernel<<<nblk_edge, 256, 0, stream>>>(ei, bcnt, bbuf);
    bscan_kernel<<<1, 1024, 0, stream>>>(bcnt, bbase);
    place_kernel<<<NB, 256, 0, stream>>>(bbuf, bcnt, bbase, row_start, col_sorted);
    repack_cheb<<<2 * HID * KDIM / 256, 256, 0, stream>>>(cheb, Bmat);
    repack_w<<<HID * KDIM / 256, 256, 0, stream>>>(W_in, Wmat);

    gemm_xw<<<nblk_gemm, 256, 0, stream>>>(x, Wmat, hA);
    spmm_gather<<<nblk_spmm, 256, 0, stream>>>(row_start, col_sorted, hA, hB);

    cheb_gemm<<<nblk_gemm, 256, 0, stream>>>(hB, Bmat, hA);                    // layer 0
    spmm_gather<<<nblk_spmm, 256, 0, stream>>>(row_start, col_sorted, hA, hB);

    cheb_gemm<<<nblk_gemm, 256, 0, stream>>>(hB, Bmat + HID * KDIM, hA);       // layer 1
    spmm_gather<<<nblk_spmm, 256, 0, stream>>>(row_start, col_sorted, hA, hB);

    out_kernel<<<nblk_out, 256, 0, stream>>>(hB, W_out, out);
}